// Round 13
// baseline (891.680 us; speedup 1.0000x reference)
//
#include <hip/hip_runtime.h>
#include <hip/hip_bf16.h>

// TemporalAttention — Round 13: k_proj fused into k_attn.
// k_attn block = (window, branch): attention -> OP (swizzled, LDS) ->
// proj phase (8 waves: pm=h&3 row-tile, pn=h>>2 j-parity; B-tiles staged in
// 16KB pairs through 2x16KB LDS double buffer) -> f32 out directly.
// Kills the 412MB o_pre HBM round-trip + the k_proj kernel.
// k_qkv (256,3), k_bias, prep_w unchanged from round 12.

typedef __attribute__((ext_vector_type(8))) short short8;
typedef __attribute__((ext_vector_type(4))) float f32x4;

#define NTOK 49
#define NWIN 4096
#define MROWS 200704        // NWIN*NTOK
#define NMT 3136            // MROWS/64
#define SCALE 0.17677669529663687f

// weight tile indices (tile = 8192 B swizzled 16x256 bf16)
#define TQ_T   0
#define TKV1_T 16
#define TKV2_T 48
#define TP1_T  80
#define TP2_T  96

// ws byte offsets (weights end at 112*8192 = 917504)
#define OFF_BIAS_B 917504ull       // [8][4][4][16][16] f32 = 131072 B
#define OFF_QN_B   1048576ull      // [wid][8][49][32] bf16
#define OFF_NRM_B  103809024ull    // [row][32] f32
#define OFF_KN2_B  129499136ull    // kn2
#define OFF_KN1_B  232259584ull    // kn1
#define OFF_V2_B   335020032ull    // v2 [wid][h][tok][32]
#define OFF_V1_B   437780480ull    // v1

__device__ __forceinline__ short f2b(float f) {
    union { float f; unsigned u; } v{f};
    unsigned r = v.u + 0x7fffu + ((v.u >> 16) & 1u);   // RNE, inputs never NaN
    return (short)(r >> 16);
}
__device__ __forceinline__ float b2f(short s) {
    return __uint_as_float(((unsigned)(unsigned short)s) << 16);
}
__device__ __forceinline__ short8 pack8(float4 a, float4 b) {
    short8 s;
    s[0]=f2b(a.x); s[1]=f2b(a.y); s[2]=f2b(a.z); s[3]=f2b(a.w);
    s[4]=f2b(b.x); s[5]=f2b(b.y); s[6]=f2b(b.z); s[7]=f2b(b.w);
    return s;
}
__device__ __forceinline__ f32x4 mfma16(short8 a, short8 b, f32x4 c) {
    return __builtin_amdgcn_mfma_f32_16x16x32_bf16(a, b, c, 0, 0, 0);
}
__device__ __forceinline__ short8 g16(const short* p) { return *(const short8*)p; }
// row-major [R][256] bf16, XOR-swizzled (512B rows)
__device__ __forceinline__ short8 ld16(const short* base, int row, int c8) {
    return *(const short8*)((const char*)base + row*512 + ((c8*2) ^ ((row&7)<<4)));
}
__device__ __forceinline__ void st2(short* base, int row, int c, short v) {
    *(short*)((char*)base + row*512 + ((c*2) ^ ((row&7)<<4))) = v;
}
// P scratch [16][64] bf16, 128B rows, XOR swizzle
__device__ __forceinline__ short8 ld16r128(const short* base, int row, int m8) {
    return *(const short8*)((const char*)base + row*128 + ((m8*2) ^ ((row&7)<<4)));
}
__device__ __forceinline__ void st2r128(short* base, int row, int m, short v) {
    *(short*)((char*)base + row*128 + ((m*2) ^ ((row&7)<<4))) = v;
}
// async global->LDS, 16B per lane
__device__ __forceinline__ void gl16(const void* g, void* l) {
    __builtin_amdgcn_global_load_lds(
        (const __attribute__((address_space(1))) unsigned*)g,
        (__attribute__((address_space(3))) unsigned*)l, 16, 0, 0);
}
// read swizzled B-frag from an 8KB LDS tile
__device__ __forceinline__ short8 ldb(const short* tile, int lr, int lg, int kb) {
    return *(const short8*)((const char*)tile + lr*512
                            + ((kb*64 + lg*16) ^ ((lr&7)<<4)));
}

// ---------------- prep_w: f32 weights -> swizzled bf16 tiles ----------------
__global__ void prep_w(const float* __restrict__ qw, const float* __restrict__ kv1,
                       const float* __restrict__ kv2, const float* __restrict__ p1,
                       const float* __restrict__ p2, short* __restrict__ ws) {
    int i = blockIdx.x * 256 + threadIdx.x;    // octet index
    int e = i * 8;
    const float* src; int rel, tbase;
    if      (e < 65536)  { src = qw;  rel = e;          tbase = TQ_T;  }
    else if (e < 196608) { src = kv1; rel = e - 65536;  tbase = TKV1_T; }
    else if (e < 327680) { src = kv2; rel = e - 196608; tbase = TKV2_T; }
    else if (e < 393216) { src = p1;  rel = e - 327680; tbase = TP1_T; }
    else                 { src = p2;  rel = e - 393216; tbase = TP2_T; }
    int row = rel >> 8, col = rel & 255;
    short8 v;
#pragma unroll
    for (int k = 0; k < 8; ++k) v[k] = f2b(src[rel + k]);
    char* dst = (char*)ws + (size_t)(tbase + (row >> 4)) * 8192
              + (row & 15) * 512 + ((col * 2) ^ ((row & 7) << 4));
    *(short8*)dst = v;
}

// ---------------- k_bias: bias[h][mt][lg][lr][nt][r] f32 ----------------
__global__ void k_bias(const int* __restrict__ rel_index,
                       const float* __restrict__ rpb, short* __restrict__ ws) {
    int i = blockIdx.x * 256 + threadIdx.x;    // 0..32767
    int r  = i & 3;
    int nt = (i >> 2) & 3;
    int lr = (i >> 4) & 15;
    int lg = (i >> 8) & 3;
    int mt = (i >> 10) & 3;
    int h  = (i >> 12) & 7;
    int m  = 16*mt + 4*lg + r;
    int mc = 16*nt + lr;
    float v = 0.f;
    if (m < NTOK && mc < NTOK) v = rpb[rel_index[m*NTOK + mc]*8 + h];
    ((float*)((char*)ws + OFF_BIAS_B))[i] = v;
}

// ---------------- k_qkv: flat GEMMs, B via LDS double-buffer ----------------
__global__ __launch_bounds__(256, 3)
void k_qkv(const float* __restrict__ x1, const float* __restrict__ x2,
           const float* __restrict__ kv1_b, const float* __restrict__ kv2_b,
           const float* __restrict__ q_b, short* __restrict__ ws)
{
    __shared__ short Bt[2][4096];              // 2 x 8 KB B-tile

    const int t    = (int)threadIdx.x;
    const int wv   = t >> 6;
    const int lane = t & 63;
    const int lr   = t & 15;
    const int lg   = (t >> 4) & 3;
    const int bid  = (int)blockIdx.x;
    const int type = bid % 3;                  // 0=q(diff), 1=kv2(x2), 2=kv1(x1)
    const int mt   = bid / 3;
    const int ar   = mt*64 + 16*wv + lr;

    unsigned widr[4], tokr[4];
#pragma unroll
    for (int r = 0; r < 4; ++r) {
        unsigned n = (unsigned)(mt*64 + 16*wv + 4*lg + r);
        widr[r] = n / 49u; tokr[r] = n - widr[r]*49u;
    }

    const char* tb = (const char*)ws
        + (size_t)(type == 0 ? TQ_T : (type == 1 ? TKV2_T : TKV1_T)) * 8192;

#define STAGE(J, B) do {                                                  \
        const char* g_ = tb + (size_t)(J)*8192 + wv*2048 + lane*16;       \
        char* l_ = (char*)Bt[(B)] + wv*2048 + lane*16;                    \
        gl16(g_, l_); gl16(g_ + 1024, l_ + 1024);                         \
    } while (0)

    if (type == 0) {
        short8 ad[8];
#pragma unroll
        for (int kb = 0; kb < 8; ++kb) {
            const float* pa = x2 + (size_t)ar*256 + kb*32 + lg*8;
            const float* pc = x1 + (size_t)ar*256 + kb*32 + lg*8;
            float4 a0 = *(const float4*)pa, a1 = *(const float4*)(pa+4);
            float4 c0 = *(const float4*)pc, c1 = *(const float4*)(pc+4);
            float4 d0 = make_float4(fabsf(a0.x-c0.x), fabsf(a0.y-c0.y),
                                    fabsf(a0.z-c0.z), fabsf(a0.w-c0.w));
            float4 d1 = make_float4(fabsf(a1.x-c1.x), fabsf(a1.y-c1.y),
                                    fabsf(a1.z-c1.z), fabsf(a1.w-c1.w));
            ad[kb] = pack8(d0, d1);
        }
        STAGE(0, 0);
        __syncthreads();
        f32x4 qa[16];
#pragma unroll
        for (int j = 0; j < 16; ++j) {
            if (j < 15) STAGE(j+1, (j+1)&1);
            const short* bt = Bt[j&1];
            f32x4 acc = {0.f,0.f,0.f,0.f};
#pragma unroll
            for (int kb = 0; kb < 8; ++kb) acc = mfma16(ad[kb], ldb(bt, lr, lg, kb), acc);
            float bj = q_b[j*16 + lr];
#pragma unroll
            for (int r = 0; r < 4; ++r) acc[r] = (acc[r] + bj) * SCALE;
            qa[j] = acc;
            __syncthreads();
        }
        short* qn  = (short*)((char*)ws + OFF_QN_B);
        float* nrm = (float*)((char*)ws + OFF_NRM_B);
#pragma unroll
        for (int r = 0; r < 4; ++r) {
            float s0 = 0.f, s1 = 0.f;
#pragma unroll
            for (int jj = 0; jj < 8; ++jj) {
                float v0 = qa[2*jj][r], v1 = qa[2*jj+1][r];
                s0 = fmaf(v0, v0, s0); s1 = fmaf(v1, v1, s1);
            }
            float n0 = fmaxf(sqrtf(s0), 1e-12f), n1 = fmaxf(sqrtf(s1), 1e-12f);
            unsigned n = widr[r]*49u + tokr[r];
            nrm[(size_t)n*32 + lr]      = n0;
            nrm[(size_t)n*32 + 16 + lr] = n1;
            float ri0 = 1.0f/n0, ri1 = 1.0f/n1;
            size_t base = ((size_t)widr[r]*392 + tokr[r])*32;
#pragma unroll
            for (int j = 0; j < 16; ++j) {
                int h = j >> 1, p = j & 1;
                qn[base + h*1568 + 16*p + lr] = f2b(qa[j][r] * (p ? ri1 : ri0));
            }
        }
    } else {
        const float* xp  = (type == 1) ? x2 : x1;
        const float* kvb = (type == 1) ? kv2_b : kv1_b;
        short* knp = (short*)((char*)ws + ((type == 1) ? OFF_KN2_B : OFF_KN1_B));
        short* vp  = (short*)((char*)ws + ((type == 1) ? OFF_V2_B  : OFF_V1_B));

        short8 ad[8];
#pragma unroll
        for (int kb = 0; kb < 8; ++kb) {
            const float* pa = xp + (size_t)ar*256 + kb*32 + lg*8;
            float4 a0 = *(const float4*)pa, a1 = *(const float4*)(pa+4);
            ad[kb] = pack8(a0, a1);
        }
        size_t base[4];
#pragma unroll
        for (int r = 0; r < 4; ++r) base[r] = ((size_t)widr[r]*392 + tokr[r])*32;

        STAGE(0, 0);
        __syncthreads();
        f32x4 ka[16];
#pragma unroll
        for (int j = 0; j < 32; ++j) {
            if (j < 31) STAGE(j+1, (j+1)&1);
            const short* bt = Bt[j&1];
            f32x4 acc = {0.f,0.f,0.f,0.f};
#pragma unroll
            for (int kb = 0; kb < 8; ++kb) acc = mfma16(ad[kb], ldb(bt, lr, lg, kb), acc);
            if (j < 16) {
                float bj = kvb[j*16 + lr];
#pragma unroll
                for (int r = 0; r < 4; ++r) acc[r] += bj;
                ka[j] = acc;
            } else {
                const int jv = j - 16;
                float bj = kvb[256 + jv*16 + lr];
                int h = jv >> 1, p = jv & 1;
#pragma unroll
                for (int r = 0; r < 4; ++r)
                    vp[base[r] + h*1568 + 16*p + lr] = f2b(acc[r] + bj);
            }
            __syncthreads();
        }
#pragma unroll
        for (int r = 0; r < 4; ++r) {
            float s0 = 0.f, s1 = 0.f;
#pragma unroll
            for (int jj = 0; jj < 8; ++jj) {
                float v0 = ka[2*jj][r], v1 = ka[2*jj+1][r];
                s0 = fmaf(v0, v0, s0); s1 = fmaf(v1, v1, s1);
            }
            float ri0 = 1.0f/fmaxf(sqrtf(s0), 1e-12f);
            float ri1 = 1.0f/fmaxf(sqrtf(s1), 1e-12f);
#pragma unroll
            for (int j = 0; j < 16; ++j) {
                int h = j >> 1, p = j & 1;
                knp[base[r] + h*1568 + 16*p + lr] = f2b(ka[j][r] * (p ? ri1 : ri0));
            }
        }
    }
#undef STAGE
}

// ---------------- k_attn: attention + fused proj per (window, branch) ----------------
__global__ __launch_bounds__(512, 2)
void k_attn(const float* __restrict__ p1_b, const float* __restrict__ p2_b,
            short* __restrict__ ws, float* __restrict__ out)
{
    __shared__ short OP[NTOK*256];    // 25088 B, swizzled 512B rows
    __shared__ short PS[8*16*64];     // 16384 B
    __shared__ short Bt[2][8192];     // 2 x 16 KB tile-pair buffer

    const int t  = (int)threadIdx.x;
    const int h  = t >> 6;            // wave = head (attn) / (pm,pn) (proj)
    const int lr = t & 15;
    const int lg = (t >> 4) & 3;
    const int bid = (int)blockIdx.x;
    const int wid = bid >> 1;
    const int br  = bid & 1;

    const short* qn  = (const short*)((const char*)ws + OFF_QN_B);
    const float* nrm = (const float*)((const char*)ws + OFF_NRM_B);
    const float* bias_t = (const float*)((const char*)ws + OFF_BIAS_B);
    short* Pb = PS + h*1024;
    const int khbase = (wid*8 + h)*49;

    const short* knp = (const short*)((const char*)ws + (br ? OFF_KN1_B : OFF_KN2_B));
    const short* vp  = (const short*)((const char*)ws + (br ? OFF_V1_B  : OFF_V2_B));
    const float subscale = br ? SCALE : 1.0f;

    // ---- attention phase ----
    short8 kf[4];
#pragma unroll
    for (int nt = 0; nt < 4; ++nt) {
        int n = min(16*nt + lr, NTOK-1);
        kf[nt] = g16(knp + (size_t)(khbase + n)*32 + lg*8);
    }
    short8 vf[2][2];
#pragma unroll
    for (int dt = 0; dt < 2; ++dt)
#pragma unroll
        for (int st = 0; st < 2; ++st) {
            short8 s8;
#pragma unroll
            for (int e = 0; e < 8; ++e) {
                int tok = st*32 + lg*8 + e;
                short v_ = 0;
                if (tok < NTOK) v_ = vp[(size_t)(khbase + tok)*32 + 16*dt + lr];
                s8[e] = v_;
            }
            vf[dt][st] = s8;
        }

#pragma unroll 1
    for (int mt = 0; mt < 4; ++mt) {
        int mrow = min(16*mt + lr, NTOK-1);
        short8 aq = g16(qn + (size_t)(khbase + mrow)*32 + lg*8);
        f32x4 S[4];
#pragma unroll
        for (int nt = 0; nt < 4; ++nt) {
            f32x4 z = {0.f,0.f,0.f,0.f};
            S[nt] = mfma16(aq, kf[nt], z);
        }
        const float4* bp4 = (const float4*)(bias_t + ((((h*4 + mt)*4 + lg)*16) + lr)*16);
        float4 bv[4];
#pragma unroll
        for (int nt = 0; nt < 4; ++nt) bv[nt] = bp4[nt];
        float sv[4][4];
#pragma unroll
        for (int nt = 0; nt < 4; ++nt) {
            bool ms = (16*nt + lr) >= NTOK;
            sv[nt][0] = ms ? -1e30f : (S[nt][0] + bv[nt].x);
            sv[nt][1] = ms ? -1e30f : (S[nt][1] + bv[nt].y);
            sv[nt][2] = ms ? -1e30f : (S[nt][2] + bv[nt].z);
            sv[nt][3] = ms ? -1e30f : (S[nt][3] + bv[nt].w);
        }
        float isum[4];
#pragma unroll
        for (int r = 0; r < 4; ++r) {
            float mx = fmaxf(fmaxf(sv[0][r], sv[1][r]), fmaxf(sv[2][r], sv[3][r]));
#pragma unroll
            for (int d = 1; d < 16; d <<= 1) mx = fmaxf(mx, __shfl_xor(mx, d));
            float e0 = __expf(sv[0][r]-mx), e1 = __expf(sv[1][r]-mx);
            float e2 = __expf(sv[2][r]-mx), e3 = __expf(sv[3][r]-mx);
            float sm = (e0+e1) + (e2+e3);
#pragma unroll
            for (int d = 1; d < 16; d <<= 1) sm += __shfl_xor(sm, d);
            isum[r] = 1.0f / sm;
            int pr = 4*lg + r;
            st2r128(Pb, pr,      lr, f2b(e0));
            st2r128(Pb, pr, 16 + lr, f2b(e1));
            st2r128(Pb, pr, 32 + lr, f2b(e2));
            st2r128(Pb, pr, 48 + lr, f2b(e3));
        }
        short8 pa0 = ld16r128(Pb, lr, lg*8);
        short8 pa1 = ld16r128(Pb, lr, 32 + lg*8);
#pragma unroll
        for (int dt = 0; dt < 2; ++dt) {
            f32x4 acc = {0.f,0.f,0.f,0.f};
            acc = mfma16(pa0, vf[dt][0], acc);
            acc = mfma16(pa1, vf[dt][1], acc);
#pragma unroll
            for (int r = 0; r < 4; ++r) {
                int m = 16*mt + 4*lg + r;
                int me = min(m, NTOK-1);
                int d = 16*dt + lr;
                float qv = b2f(qn[(size_t)(khbase + me)*32 + d]);
                float nv = nrm[((size_t)wid*NTOK + me)*32 + d];
                float o = acc[r]*isum[r] - qv*nv*subscale;
                if (m < NTOK) st2(OP, m, h*32 + d, f2b(o));
            }
        }
    }
    __syncthreads();

    // ---- fused proj phase: out = OP @ Wp^T + pb ----
    {
        const int pm = h & 3, pn = h >> 2;
        const char* tb = (const char*)ws + (size_t)(br ? TP2_T : TP1_T) * 8192;
        const float* pjb = br ? p2_b : p1_b;
        float* outp = out + (size_t)br*((size_t)MROWS*256) + (size_t)wid*(NTOK*256);
        const int parow = min(16*pm + lr, NTOK-1);

        short8 ad[8];
#pragma unroll
        for (int kb = 0; kb < 8; ++kb) ad[kb] = ld16(OP, parow, kb*32 + lg*8);

        // stage tile-pair jj -> Bt[B] (16 KB: 512 thr x 2 x 16 B)
#define STAGEP(JJ, B) do {                                                \
        const char* g_ = tb + (size_t)(JJ)*16384 + t*16;                  \
        char* l_ = (char*)Bt[(B)] + t*16;                                 \
        gl16(g_, l_); gl16(g_ + 8192, l_ + 8192);                         \
    } while (0)

        STAGEP(0, 0);
        __syncthreads();
#pragma unroll 1
        for (int jj = 0; jj < 8; ++jj) {
            if (jj < 7) STAGEP(jj+1, (jj+1)&1);
            const short* bt = (const short*)((const char*)Bt[jj&1] + pn*8192);
            f32x4 acc = {0.f,0.f,0.f,0.f};
#pragma unroll
            for (int kb = 0; kb < 8; ++kb) acc = mfma16(ad[kb], ldb(bt, lr, lg, kb), acc);
            const int t16 = 2*jj + pn;
            float bj = pjb[t16*16 + lr];
#pragma unroll
            for (int r = 0; r < 4; ++r) {
                int n = 16*pm + 4*lg + r;
                if (n < NTOK) outp[(size_t)n*256 + 16*t16 + lr] = acc[r] + bj;
            }
            __syncthreads();
        }
#undef STAGEP
    }
}

extern "C" void kernel_launch(void* const* d_in, const int* in_sizes, int n_in,
                              void* d_out, int out_size, void* d_ws, size_t ws_size,
                              hipStream_t stream) {
    (void)in_sizes; (void)n_in; (void)ws_size; (void)out_size;
    const float* x1   = (const float*)d_in[0];
    const float* x2   = (const float*)d_in[1];
    const int*   rel  = (const int*)  d_in[2];
    const float* kv1w = (const float*)d_in[3];
    const float* kv1b = (const float*)d_in[4];
    const float* kv2w = (const float*)d_in[5];
    const float* kv2b = (const float*)d_in[6];
    const float* qw   = (const float*)d_in[7];
    const float* qb   = (const float*)d_in[8];
    const float* rpb  = (const float*)d_in[9];
    const float* p1w  = (const float*)d_in[10];
    const float* p1b  = (const float*)d_in[11];
    const float* p2w  = (const float*)d_in[12];
    const float* p2b  = (const float*)d_in[13];
    float* out = (float*)d_out;
    short* ws  = (short*)d_ws;

    hipLaunchKernelGGL(prep_w, dim3(224), dim3(256), 0, stream,
                       qw, kv1w, kv2w, p1w, p2w, ws);
    hipLaunchKernelGGL(k_bias, dim3(128), dim3(256), 0, stream,
                       rel, rpb, ws);
    hipLaunchKernelGGL(k_qkv, dim3(NMT*3), dim3(256), 0, stream,
                       x1, x2, kv1b, kv2b, qb, ws);
    hipLaunchKernelGGL(k_attn, dim3(NWIN*2), dim3(512), 0, stream,
                       p1b, p2b, ws, out);
}

// Round 14
// 832.252 us; speedup vs baseline: 1.0714x; 1.0714x over previous
//
#include <hip/hip_runtime.h>
#include <hip/hip_bf16.h>

// TemporalAttention — Round 14: round-12 structure (fusion reverted) with
// DOUBLE-WIDTH B staging: 16KB tile-pairs per stage in k_qkv/k_proj.
// Rationale: per-stage compute (was 8 MFMA ~140cy) could not cover the
// stage latency drained by each __syncthreads (~400-600cy); pairs give
// 16 MFMA per stage and halve the barrier count.
// k_attn = round-12 version verbatim (branch-split, bias table, o_pre overlay).

typedef __attribute__((ext_vector_type(8))) short short8;
typedef __attribute__((ext_vector_type(4))) float f32x4;

#define NTOK 49
#define NWIN 4096
#define MROWS 200704        // NWIN*NTOK
#define NMT 3136            // MROWS/64
#define SCALE 0.17677669529663687f

// weight tile indices (tile = 8192 B swizzled 16x256 bf16)
#define TQ_T   0
#define TKV1_T 16
#define TKV2_T 48
#define TP1_T  80
#define TP2_T  96

// ws byte offsets (weights end at 112*8192 = 917504)
#define OFF_BIAS_B 917504ull       // [8][4][4][16][16] f32 = 131072 B
#define OFF_QN_B   1048576ull      // [wid][8][49][32] bf16
#define OFF_NRM_B  103809024ull    // [row][32] f32
#define OFF_KN2_B  129499136ull    // kn2 -> o_pre br0 overlay
#define OFF_KN1_B  232259584ull    // kn1 -> o_pre br1 overlay
#define OFF_V2_B   335020032ull    // v2 [wid][h][tok][32]
#define OFF_V1_B   437780480ull    // v1

__device__ __forceinline__ short f2b(float f) {
    union { float f; unsigned u; } v{f};
    unsigned r = v.u + 0x7fffu + ((v.u >> 16) & 1u);   // RNE, inputs never NaN
    return (short)(r >> 16);
}
__device__ __forceinline__ float b2f(short s) {
    return __uint_as_float(((unsigned)(unsigned short)s) << 16);
}
__device__ __forceinline__ short8 pack8(float4 a, float4 b) {
    short8 s;
    s[0]=f2b(a.x); s[1]=f2b(a.y); s[2]=f2b(a.z); s[3]=f2b(a.w);
    s[4]=f2b(b.x); s[5]=f2b(b.y); s[6]=f2b(b.z); s[7]=f2b(b.w);
    return s;
}
__device__ __forceinline__ f32x4 mfma16(short8 a, short8 b, f32x4 c) {
    return __builtin_amdgcn_mfma_f32_16x16x32_bf16(a, b, c, 0, 0, 0);
}
__device__ __forceinline__ short8 g16(const short* p) { return *(const short8*)p; }
// P scratch [16][64] bf16, 128B rows, XOR swizzle
__device__ __forceinline__ short8 ld16r128(const short* base, int row, int m8) {
    return *(const short8*)((const char*)base + row*128 + ((m8*2) ^ ((row&7)<<4)));
}
__device__ __forceinline__ void st2r128(short* base, int row, int m, short v) {
    *(short*)((char*)base + row*128 + ((m*2) ^ ((row&7)<<4))) = v;
}
// async global->LDS, 16B per lane
__device__ __forceinline__ void gl16(const void* g, void* l) {
    __builtin_amdgcn_global_load_lds(
        (const __attribute__((address_space(1))) unsigned*)g,
        (__attribute__((address_space(3))) unsigned*)l, 16, 0, 0);
}
// read swizzled B-frag from an 8KB LDS tile
__device__ __forceinline__ short8 ldb(const short* tile, int lr, int lg, int kb) {
    return *(const short8*)((const char*)tile + lr*512
                            + ((kb*64 + lg*16) ^ ((lr&7)<<4)));
}

// ---------------- prep_w: f32 weights -> swizzled bf16 tiles ----------------
__global__ void prep_w(const float* __restrict__ qw, const float* __restrict__ kv1,
                       const float* __restrict__ kv2, const float* __restrict__ p1,
                       const float* __restrict__ p2, short* __restrict__ ws) {
    int i = blockIdx.x * 256 + threadIdx.x;    // octet index
    int e = i * 8;
    const float* src; int rel, tbase;
    if      (e < 65536)  { src = qw;  rel = e;          tbase = TQ_T;  }
    else if (e < 196608) { src = kv1; rel = e - 65536;  tbase = TKV1_T; }
    else if (e < 327680) { src = kv2; rel = e - 196608; tbase = TKV2_T; }
    else if (e < 393216) { src = p1;  rel = e - 327680; tbase = TP1_T; }
    else                 { src = p2;  rel = e - 393216; tbase = TP2_T; }
    int row = rel >> 8, col = rel & 255;
    short8 v;
#pragma unroll
    for (int k = 0; k < 8; ++k) v[k] = f2b(src[rel + k]);
    char* dst = (char*)ws + (size_t)(tbase + (row >> 4)) * 8192
              + (row & 15) * 512 + ((col * 2) ^ ((row & 7) << 4));
    *(short8*)dst = v;
}

// ---------------- k_bias: bias[h][mt][lg][lr][nt][r] f32 ----------------
__global__ void k_bias(const int* __restrict__ rel_index,
                       const float* __restrict__ rpb, short* __restrict__ ws) {
    int i = blockIdx.x * 256 + threadIdx.x;    // 0..32767
    int r  = i & 3;
    int nt = (i >> 2) & 3;
    int lr = (i >> 4) & 15;
    int lg = (i >> 8) & 3;
    int mt = (i >> 10) & 3;
    int h  = (i >> 12) & 7;
    int m  = 16*mt + 4*lg + r;
    int mc = 16*nt + lr;
    float v = 0.f;
    if (m < NTOK && mc < NTOK) v = rpb[rel_index[m*NTOK + mc]*8 + h];
    ((float*)((char*)ws + OFF_BIAS_B))[i] = v;
}

// ---------------- k_qkv: flat GEMMs, 16KB tile-pair LDS double-buffer ----------------
__global__ __launch_bounds__(256, 3)
void k_qkv(const float* __restrict__ x1, const float* __restrict__ x2,
           const float* __restrict__ kv1_b, const float* __restrict__ kv2_b,
           const float* __restrict__ q_b, short* __restrict__ ws)
{
    __shared__ short Bt[2][8192];              // 2 x 16 KB tile-pair

    const int t    = (int)threadIdx.x;
    const int lr   = t & 15;
    const int lg   = (t >> 4) & 3;
    const int bid  = (int)blockIdx.x;
    const int type = bid % 3;                  // 0=q(diff), 1=kv2(x2), 2=kv1(x1)
    const int mt   = bid / 3;
    const int wv   = t >> 6;
    const int ar   = mt*64 + 16*wv + lr;

    unsigned widr[4], tokr[4];
#pragma unroll
    for (int r = 0; r < 4; ++r) {
        unsigned n = (unsigned)(mt*64 + 16*wv + 4*lg + r);
        widr[r] = n / 49u; tokr[r] = n - widr[r]*49u;
    }

    const char* tb = (const char*)ws
        + (size_t)(type == 0 ? TQ_T : (type == 1 ? TKV2_T : TKV1_T)) * 8192;

// stage tile-pair J2 (16 KB) into Bt[B]: 256 thr x 4 x 16 B
#define STAGE2(J2, B) do {                                                \
        const char* g_ = tb + (size_t)(J2)*16384 + t*16;                  \
        char* l_ = (char*)Bt[(B)] + t*16;                                 \
        gl16(g_, l_); gl16(g_ + 4096, l_ + 4096);                         \
        gl16(g_ + 8192, l_ + 8192); gl16(g_ + 12288, l_ + 12288);         \
    } while (0)

    if (type == 0) {
        short8 ad[8];
#pragma unroll
        for (int kb = 0; kb < 8; ++kb) {
            const float* pa = x2 + (size_t)ar*256 + kb*32 + lg*8;
            const float* pc = x1 + (size_t)ar*256 + kb*32 + lg*8;
            float4 a0 = *(const float4*)pa, a1 = *(const float4*)(pa+4);
            float4 c0 = *(const float4*)pc, c1 = *(const float4*)(pc+4);
            float4 d0 = make_float4(fabsf(a0.x-c0.x), fabsf(a0.y-c0.y),
                                    fabsf(a0.z-c0.z), fabsf(a0.w-c0.w));
            float4 d1 = make_float4(fabsf(a1.x-c1.x), fabsf(a1.y-c1.y),
                                    fabsf(a1.z-c1.z), fabsf(a1.w-c1.w));
            ad[kb] = pack8(d0, d1);
        }
        STAGE2(0, 0);
        __syncthreads();
        f32x4 qa[16];
#pragma unroll
        for (int jj = 0; jj < 8; ++jj) {
            if (jj < 7) STAGE2(jj+1, (jj+1)&1);
            const short* btp = Bt[jj&1];
#pragma unroll
            for (int e = 0; e < 2; ++e) {
                const int j = 2*jj + e;
                const short* bt = btp + e*4096;
                f32x4 acc = {0.f,0.f,0.f,0.f};
#pragma unroll
                for (int kb = 0; kb < 8; ++kb) acc = mfma16(ad[kb], ldb(bt, lr, lg, kb), acc);
                float bj = q_b[j*16 + lr];
#pragma unroll
                for (int r = 0; r < 4; ++r) acc[r] = (acc[r] + bj) * SCALE;
                qa[j] = acc;
            }
            __syncthreads();
        }
        short* qn  = (short*)((char*)ws + OFF_QN_B);
        float* nrm = (float*)((char*)ws + OFF_NRM_B);
#pragma unroll
        for (int r = 0; r < 4; ++r) {
            float s0 = 0.f, s1 = 0.f;
#pragma unroll
            for (int jj = 0; jj < 8; ++jj) {
                float v0 = qa[2*jj][r], v1 = qa[2*jj+1][r];
                s0 = fmaf(v0, v0, s0); s1 = fmaf(v1, v1, s1);
            }
            float n0 = fmaxf(sqrtf(s0), 1e-12f), n1 = fmaxf(sqrtf(s1), 1e-12f);
            unsigned n = widr[r]*49u + tokr[r];
            nrm[(size_t)n*32 + lr]      = n0;
            nrm[(size_t)n*32 + 16 + lr] = n1;
            float ri0 = 1.0f/n0, ri1 = 1.0f/n1;
            size_t base = ((size_t)widr[r]*392 + tokr[r])*32;
#pragma unroll
            for (int j = 0; j < 16; ++j) {
                int h = j >> 1, p = j & 1;
                qn[base + h*1568 + 16*p + lr] = f2b(qa[j][r] * (p ? ri1 : ri0));
            }
        }
    } else {
        const float* xp  = (type == 1) ? x2 : x1;
        const float* kvb = (type == 1) ? kv2_b : kv1_b;
        short* knp = (short*)((char*)ws + ((type == 1) ? OFF_KN2_B : OFF_KN1_B));
        short* vp  = (short*)((char*)ws + ((type == 1) ? OFF_V2_B  : OFF_V1_B));

        short8 ad[8];
#pragma unroll
        for (int kb = 0; kb < 8; ++kb) {
            const float* pa = xp + (size_t)ar*256 + kb*32 + lg*8;
            float4 a0 = *(const float4*)pa, a1 = *(const float4*)(pa+4);
            ad[kb] = pack8(a0, a1);
        }
        size_t base[4];
#pragma unroll
        for (int r = 0; r < 4; ++r) base[r] = ((size_t)widr[r]*392 + tokr[r])*32;

        STAGE2(0, 0);
        __syncthreads();
        f32x4 ka[16];
#pragma unroll
        for (int jj = 0; jj < 16; ++jj) {
            if (jj < 15) STAGE2(jj+1, (jj+1)&1);
            const short* btp = Bt[jj&1];
#pragma unroll
            for (int e = 0; e < 2; ++e) {
                const int j = 2*jj + e;
                const short* bt = btp + e*4096;
                f32x4 acc = {0.f,0.f,0.f,0.f};
#pragma unroll
                for (int kb = 0; kb < 8; ++kb) acc = mfma16(ad[kb], ldb(bt, lr, lg, kb), acc);
                if (j < 16) {
                    float bj = kvb[j*16 + lr];
#pragma unroll
                    for (int r = 0; r < 4; ++r) acc[r] += bj;
                    ka[j] = acc;
                } else {
                    const int jv = j - 16;
                    float bj = kvb[256 + jv*16 + lr];
                    int h = jv >> 1, p = jv & 1;
#pragma unroll
                    for (int r = 0; r < 4; ++r)
                        vp[base[r] + h*1568 + 16*p + lr] = f2b(acc[r] + bj);
                }
            }
            __syncthreads();
        }
#pragma unroll
        for (int r = 0; r < 4; ++r) {
            float s0 = 0.f, s1 = 0.f;
#pragma unroll
            for (int jj = 0; jj < 8; ++jj) {
                float v0 = ka[2*jj][r], v1 = ka[2*jj+1][r];
                s0 = fmaf(v0, v0, s0); s1 = fmaf(v1, v1, s1);
            }
            float ri0 = 1.0f/fmaxf(sqrtf(s0), 1e-12f);
            float ri1 = 1.0f/fmaxf(sqrtf(s1), 1e-12f);
#pragma unroll
            for (int j = 0; j < 16; ++j) {
                int h = j >> 1, p = j & 1;
                knp[base[r] + h*1568 + 16*p + lr] = f2b(ka[j][r] * (p ? ri1 : ri0));
            }
        }
    }
#undef STAGE2
}

// ---------------- k_attn: one block per (window, branch) — round-12 verbatim ----------------
__global__ __launch_bounds__(512, 2)
void k_attn(short* __restrict__ ws)
{
    __shared__ short OP[NTOK*256];    // 25088 B
    __shared__ short PS[8*16*64];     // 16384 B

    const int t  = (int)threadIdx.x;
    const int h  = t >> 6;            // wave = head
    const int lr = t & 15;
    const int lg = (t >> 4) & 3;
    const int bid = (int)blockIdx.x;
    const int wid = bid >> 1;
    const int br  = bid & 1;

    const short* qn  = (const short*)((const char*)ws + OFF_QN_B);
    const float* nrm = (const float*)((const char*)ws + OFF_NRM_B);
    const float* bias_t = (const float*)((const char*)ws + OFF_BIAS_B);
    short* Pb = PS + h*1024;
    const int khbase = (wid*8 + h)*49;

    const short* knp = (const short*)((const char*)ws + (br ? OFF_KN1_B : OFF_KN2_B));
    const short* vp  = (const short*)((const char*)ws + (br ? OFF_V1_B  : OFF_V2_B));
    short* opre = (short*)((char*)ws + (br ? OFF_KN1_B : OFF_KN2_B));  // overlay
    const float subscale = br ? SCALE : 1.0f;

    short8 kf[4];
#pragma unroll
    for (int nt = 0; nt < 4; ++nt) {
        int n = min(16*nt + lr, NTOK-1);
        kf[nt] = g16(knp + (size_t)(khbase + n)*32 + lg*8);
    }
    short8 vf[2][2];
#pragma unroll
    for (int dt = 0; dt < 2; ++dt)
#pragma unroll
        for (int st = 0; st < 2; ++st) {
            short8 s8;
#pragma unroll
            for (int e = 0; e < 8; ++e) {
                int tok = st*32 + lg*8 + e;
                short v_ = 0;
                if (tok < NTOK) v_ = vp[(size_t)(khbase + tok)*32 + 16*dt + lr];
                s8[e] = v_;
            }
            vf[dt][st] = s8;
        }

#pragma unroll 1
    for (int mt = 0; mt < 4; ++mt) {
        int mrow = min(16*mt + lr, NTOK-1);
        short8 aq = g16(qn + (size_t)(khbase + mrow)*32 + lg*8);
        f32x4 S[4];
#pragma unroll
        for (int nt = 0; nt < 4; ++nt) {
            f32x4 z = {0.f,0.f,0.f,0.f};
            S[nt] = mfma16(aq, kf[nt], z);
        }
        const float4* bp4 = (const float4*)(bias_t + ((((h*4 + mt)*4 + lg)*16) + lr)*16);
        float4 bv[4];
#pragma unroll
        for (int nt = 0; nt < 4; ++nt) bv[nt] = bp4[nt];
        float sv[4][4];
#pragma unroll
        for (int nt = 0; nt < 4; ++nt) {
            bool ms = (16*nt + lr) >= NTOK;
            sv[nt][0] = ms ? -1e30f : (S[nt][0] + bv[nt].x);
            sv[nt][1] = ms ? -1e30f : (S[nt][1] + bv[nt].y);
            sv[nt][2] = ms ? -1e30f : (S[nt][2] + bv[nt].z);
            sv[nt][3] = ms ? -1e30f : (S[nt][3] + bv[nt].w);
        }
        float isum[4];
#pragma unroll
        for (int r = 0; r < 4; ++r) {
            float mx = fmaxf(fmaxf(sv[0][r], sv[1][r]), fmaxf(sv[2][r], sv[3][r]));
#pragma unroll
            for (int d = 1; d < 16; d <<= 1) mx = fmaxf(mx, __shfl_xor(mx, d));
            float e0 = __expf(sv[0][r]-mx), e1 = __expf(sv[1][r]-mx);
            float e2 = __expf(sv[2][r]-mx), e3 = __expf(sv[3][r]-mx);
            float sm = (e0+e1) + (e2+e3);
#pragma unroll
            for (int d = 1; d < 16; d <<= 1) sm += __shfl_xor(sm, d);
            isum[r] = 1.0f / sm;
            int pr = 4*lg + r;
            st2r128(Pb, pr,      lr, f2b(e0));
            st2r128(Pb, pr, 16 + lr, f2b(e1));
            st2r128(Pb, pr, 32 + lr, f2b(e2));
            st2r128(Pb, pr, 48 + lr, f2b(e3));
        }
        short8 pa0 = ld16r128(Pb, lr, lg*8);
        short8 pa1 = ld16r128(Pb, lr, 32 + lg*8);
#pragma unroll
        for (int dt = 0; dt < 2; ++dt) {
            f32x4 acc = {0.f,0.f,0.f,0.f};
            acc = mfma16(pa0, vf[dt][0], acc);
            acc = mfma16(pa1, vf[dt][1], acc);
#pragma unroll
            for (int r = 0; r < 4; ++r) {
                int m = 16*mt + 4*lg + r;
                int me = min(m, NTOK-1);
                int d = 16*dt + lr;
                float qv = b2f(qn[(size_t)(khbase + me)*32 + d]);
                float nv = nrm[((size_t)wid*NTOK + me)*32 + d];
                float o = acc[r]*isum[r] - qv*nv*subscale;
                if (m < NTOK) OP[m*256 + h*32 + d] = f2b(o);
            }
        }
    }
    __syncthreads();
    {
        const short8* sp = (const short8*)OP;
        short8* dp = (short8*)(opre + (size_t)wid*NTOK*256);
        for (int i = t; i < NTOK*256/8; i += 512) dp[i] = sp[i];
    }
}

// ---------------- k_proj: flat proj GEMM, 16KB tile-pair double-buffer ----------------
__global__ __launch_bounds__(256, 3)
void k_proj(const float* __restrict__ p1_b, const float* __restrict__ p2_b,
            const short* __restrict__ ws, float* __restrict__ out)
{
    __shared__ short Bt[2][8192];

    const int t    = (int)threadIdx.x;
    const int wv   = t >> 6;
    const int lr   = t & 15;
    const int lg   = (t >> 4) & 3;
    const int bid  = (int)blockIdx.x;
    const int br   = bid & 1;
    const int mt   = bid >> 1;
    const int ar   = mt*64 + 16*wv + lr;

    const char* tb = (const char*)ws + (size_t)(br ? TP2_T : TP1_T) * 8192;
    const short* op  = (const short*)((const char*)ws + (br ? OFF_KN1_B : OFF_KN2_B));
    const float* pjb = br ? p2_b : p1_b;
    float* outp = out + (size_t)br*((size_t)MROWS*256);

    short8 ad[8];
#pragma unroll
    for (int kb = 0; kb < 8; ++kb) ad[kb] = g16(op + (size_t)ar*256 + kb*32 + lg*8);

#define STAGE2(J2, B) do {                                                \
        const char* g_ = tb + (size_t)(J2)*16384 + t*16;                  \
        char* l_ = (char*)Bt[(B)] + t*16;                                 \
        gl16(g_, l_); gl16(g_ + 4096, l_ + 4096);                         \
        gl16(g_ + 8192, l_ + 8192); gl16(g_ + 12288, l_ + 12288);         \
    } while (0)

    STAGE2(0, 0);
    __syncthreads();
#pragma unroll 1
    for (int jj = 0; jj < 8; ++jj) {
        if (jj < 7) STAGE2(jj+1, (jj+1)&1);
        const short* btp = Bt[jj&1];
#pragma unroll
        for (int e = 0; e < 2; ++e) {
            const int j = 2*jj + e;
            const short* bt = btp + e*4096;
            f32x4 acc = {0.f,0.f,0.f,0.f};
#pragma unroll
            for (int kb = 0; kb < 8; ++kb) acc = mfma16(ad[kb], ldb(bt, lr, lg, kb), acc);
            float bj = pjb[j*16 + lr];
#pragma unroll
            for (int r = 0; r < 4; ++r) {
                int n = mt*64 + 16*wv + 4*lg + r;
                outp[(size_t)n*256 + j*16 + lr] = acc[r] + bj;
            }
        }
        __syncthreads();
    }
#undef STAGE2
}

extern "C" void kernel_launch(void* const* d_in, const int* in_sizes, int n_in,
                              void* d_out, int out_size, void* d_ws, size_t ws_size,
                              hipStream_t stream) {
    (void)in_sizes; (void)n_in; (void)ws_size; (void)out_size;
    const float* x1   = (const float*)d_in[0];
    const float* x2   = (const float*)d_in[1];
    const int*   rel  = (const int*)  d_in[2];
    const float* kv1w = (const float*)d_in[3];
    const float* kv1b = (const float*)d_in[4];
    const float* kv2w = (const float*)d_in[5];
    const float* kv2b = (const float*)d_in[6];
    const float* qw   = (const float*)d_in[7];
    const float* qb   = (const float*)d_in[8];
    const float* rpb  = (const float*)d_in[9];
    const float* p1w  = (const float*)d_in[10];
    const float* p1b  = (const float*)d_in[11];
    const float* p2w  = (const float*)d_in[12];
    const float* p2b  = (const float*)d_in[13];
    float* out = (float*)d_out;
    short* ws  = (short*)d_ws;

    hipLaunchKernelGGL(prep_w, dim3(224), dim3(256), 0, stream,
                       qw, kv1w, kv2w, p1w, p2w, ws);
    hipLaunchKernelGGL(k_bias, dim3(128), dim3(256), 0, stream,
                       rel, rpb, ws);
    hipLaunchKernelGGL(k_qkv, dim3(NMT*3), dim3(256), 0, stream,
                       x1, x2, kv1b, kv2b, qb, ws);
    hipLaunchKernelGGL(k_attn, dim3(NWIN*2), dim3(512), 0, stream, ws);
    hipLaunchKernelGGL(k_proj, dim3(NMT*2), dim3(256), 0, stream,
                       p1b, p2b, (const short*)ws, out);
}